// Round 3
// baseline (506.937 us; speedup 1.0000x reference)
//
#include <hip/hip_runtime.h>

#define MFULL 16384
#define MOUT  2048
#define H     4096
#define WS    8
#define BK    64
#define BM    128
#define BN    256
#define NT    (H / BK)

typedef _Float16 f16x8 __attribute__((ext_vector_type(8)));
typedef _Float16 f16x4 __attribute__((ext_vector_type(4)));
typedef _Float16 f16x2 __attribute__((ext_vector_type(2)));
typedef float    f32x4 __attribute__((ext_vector_type(4)));
typedef float    f32x2 __attribute__((ext_vector_type(2)));

// fp8(e4m3 OCP, RNE) round-trip via HW cvt instructions
__device__ __forceinline__ void fp8_rt4(float4& v) {
    int p0 = __builtin_amdgcn_cvt_pk_fp8_f32(v.x, v.y, 0, false);
    int p1 = __builtin_amdgcn_cvt_pk_fp8_f32(v.z, v.w, 0, false);
    f32x2 r0 = __builtin_amdgcn_cvt_pk_f32_fp8(p0, false);
    f32x2 r1 = __builtin_amdgcn_cvt_pk_f32_fp8(p1, false);
    v.x = r0.x; v.y = r0.y; v.z = r1.x; v.w = r1.y;
}

__device__ __forceinline__ void async_copy16(const void* g, void* l) {
    __builtin_amdgcn_global_load_lds(
        (const __attribute__((address_space(1))) void*)g,
        (__attribute__((address_space(3))) void*)l, 16, 0, 0);
}

// fp8 byte-octet -> f16x8 (exact: fp8 values are a subset of f16)
__device__ __forceinline__ f16x8 bfrag(const unsigned char* p) {
    const int2 w = *(const int2*)p;
    f32x2 a = __builtin_amdgcn_cvt_pk_f32_fp8(w.x, false);
    f32x2 b = __builtin_amdgcn_cvt_pk_f32_fp8(w.x, true);
    f32x2 c = __builtin_amdgcn_cvt_pk_f32_fp8(w.y, false);
    f32x2 d = __builtin_amdgcn_cvt_pk_f32_fp8(w.y, true);
    f16x8 r;
    r[0] = (_Float16)a.x; r[1] = (_Float16)a.y;
    r[2] = (_Float16)b.x; r[3] = (_Float16)b.y;
    r[4] = (_Float16)c.x; r[5] = (_Float16)c.y;
    r[6] = (_Float16)d.x; r[7] = (_Float16)d.y;
    return r;
}

// Pass 1a: A'[r,k] = sum_{s=0..7} fp8(input[s*2048+r, k]), stored fp16.
__global__ void reduce_quant_a(const float* __restrict__ in,
                               _Float16* __restrict__ aq) {
    int idx = blockIdx.x * 256 + threadIdx.x;
    int r = idx >> 10;
    int k = (idx & 1023) * 4;
    const float* p = in + (size_t)r * H + k;
    float4 acc = {0.f, 0.f, 0.f, 0.f};
#pragma unroll
    for (int s = 0; s < WS; ++s) {
        float4 v = *(const float4*)(p + (size_t)s * MOUT * H);
        fp8_rt4(v);
        acc.x += v.x; acc.y += v.y; acc.z += v.z; acc.w += v.w;
    }
    f16x4 h = { (_Float16)acc.x, (_Float16)acc.y, (_Float16)acc.z, (_Float16)acc.w };
    *(f16x4*)(aq + (size_t)r * H + k) = h;
}

// Pass 1b: B^T[n,k] = fp8-byte(weight[k,n]). 64x64 tile transpose via LDS.
// Stores RAW fp8 bytes (not fp16): halves Bt HBM traffic AND, downstream,
// halves the GEMM's B LDS bytes (the binding resource).
__global__ void quant_transpose_b(const float* __restrict__ w,
                                  unsigned char* __restrict__ bt) {
    __shared__ unsigned char tile[64][68];
    int t  = threadIdx.x;
    int n0 = blockIdx.x * 64;
    int k0 = blockIdx.y * 64;
#pragma unroll
    for (int i = 0; i < 4; ++i) {
        int lin = i * 256 + t;
        int kl = lin >> 4;              // row 0..63 (k)
        int nl = (lin & 15) * 4;        // col 0,4,..,60 (n)
        float4 v = *(const float4*)(w + (size_t)(k0 + kl) * H + n0 + nl);
        int p0 = __builtin_amdgcn_cvt_pk_fp8_f32(v.x, v.y, 0, false);
        int p  = __builtin_amdgcn_cvt_pk_fp8_f32(v.z, v.w, p0, true);
        // byte j of p = fp8(v[j]) = n-value nl+j (LLVM: a->[7:0], b->[15:8])
        tile[nl + 0][kl] = (unsigned char)(p & 0xff);
        tile[nl + 1][kl] = (unsigned char)((p >> 8) & 0xff);
        tile[nl + 2][kl] = (unsigned char)((p >> 16) & 0xff);
        tile[nl + 3][kl] = (unsigned char)((p >> 24) & 0xff);
    }
    __syncthreads();
    // 64 rows x 64 B out; 256 threads x 16 B
    int n  = t >> 2;
    int kc = (t & 3) * 16;
    int4 o;
    o.x = *(const int*)&tile[n][kc + 0];
    o.y = *(const int*)&tile[n][kc + 4];
    o.z = *(const int*)&tile[n][kc + 8];
    o.w = *(const int*)&tile[n][kc + 12];
    *(int4*)(bt + (size_t)(n0 + n) * H + k0 + kc) = o;
}

// Pass 2: C[2048,4096] = A' @ B' (B' as fp8 B^T [N][K]), scale_b epilogue.
//
// 4-phase K-step (T3+T4+T5), 128x256 tile, 512 threads (8 waves, 2x4 of
// 64x64), grid 16x16 = 256 blocks = 1 block/CU.
//   - A staged fp16 (sum of 8 fp8 shards needs f16 precision); B staged as
//     RAW fp8 bytes: per K-step per CU, LDS traffic drops 176KB -> 128KB
//     (B write 32->16KB, B frag reads b128->b64 64->32KB). B decoded
//     fp8->f16 in VALU (exact) right before the MFMA.
//   - 3 LDS buffers (96 KB), prefetch depth 2; 4 staging loads/thread per
//     K-step (2 A + 2 B) spread over phases 0-1; phase 3 waits
//     s_waitcnt vmcnt(4) -- NEVER 0 in the main loop.
//   - raw s_barrier + "memory" fences; s_setprio(1) around MFMA clusters.
// Swizzles (inverse-swizzled global source, linear LDS dest):
//   A (128B rows, 16B slots): slot s holds k-chunk kc = s ^ ((row>>1)&7).
//   B (64B rows, 16B slots):  slot s holds k16-chunk g = s ^ ((row>>1)&3);
//     frag ds_read_b64 at row*64 + s16*16 + (q&1)*8 -> 4 touches/bank,
//     perfectly balanced (conflict-free).
__global__ __launch_bounds__(512, 2) void gemm_rs(
    const _Float16* __restrict__ A, const unsigned char* __restrict__ Bt,
    const float* __restrict__ scale_b, float* __restrict__ out) {
    __shared__ _Float16      As[3][BM * BK];   // 3 x 16 KB
    __shared__ unsigned char Bs[3][BN * BK];   // 3 x 16 KB

    const int tid  = threadIdx.x;
    const int wid  = tid >> 6;           // 0..7
    const int lane = tid & 63;
    const int quad = lane >> 4;
    const int l16  = lane & 15;
    const int bm   = blockIdx.y * BM;
    const int bn   = blockIdx.x * BN;
    const int wm   = (wid >> 2) * 64;    // 0,64
    const int wn   = (wid & 3) * 64;     // 0,64,128,192

    f32x4 acc[4][4] = {};

    const _Float16*      Ab = A  + (size_t)bm * H;
    const unsigned char* Bb = Bt + (size_t)bn * H;

    // A staging: 1024 16B chunks (2/thread). c: row=c>>3, slot=c&7,
    // kc = slot ^ ((row>>1)&7); LDS dest = c*16 (lane-linear).
    size_t gaA[2]; int laA[2];
#pragma unroll
    for (int u = 0; u < 2; ++u) {
        int c = u * 512 + tid;
        int row = c >> 3, slot = c & 7;
        int kc = slot ^ ((row >> 1) & 7);
        gaA[u] = (size_t)row * H + kc * 8;   // elements (fp16)
        laA[u] = c * 16;
    }
    // B staging: 1024 16B chunks (2/thread). c: row=c>>2, slot=c&3,
    // g = slot ^ ((row>>1)&3); source offset in BYTES.
    size_t gaB[2]; int laB[2];
#pragma unroll
    for (int u = 0; u < 2; ++u) {
        int c = u * 512 + tid;
        int row = c >> 2, slot = c & 3;
        int g = slot ^ ((row >> 1) & 3);
        gaB[u] = (size_t)row * H + g * 16;   // bytes (fp8)
        laB[u] = c * 16;
    }

    // fragment offsets (loop-invariant)
    int aOff[4][2];   // elements into As
    int bOff[4][2];   // bytes into Bs
#pragma unroll
    for (int i = 0; i < 4; ++i) {
        int rowA = wm + i * 16 + l16;
        int rowB = wn + i * 16 + l16;
#pragma unroll
        for (int h = 0; h < 2; ++h) {
            int q  = h * 4 + quad;
            int sA = q ^ ((rowA >> 1) & 7);
            aOff[i][h] = rowA * BK + sA * 8;
            int s16 = (q >> 1) ^ ((rowB >> 1) & 3);
            bOff[i][h] = rowB * 64 + s16 * 16 + (q & 1) * 8;
        }
    }

#define FENCE asm volatile("" ::: "memory")
#define BAR   __builtin_amdgcn_s_barrier()

    // 4 MFMAs: column j of the wave tile, one A-fragment set
#define MG(afv, bfv, j)                                                     \
    _Pragma("unroll")                                                       \
    for (int i = 0; i < 4; ++i)                                             \
        acc[i][j] = __builtin_amdgcn_mfma_f32_16x16x32_f16(                 \
            afv[i], bfv, acc[i][j], 0, 0, 0);

#define STAGE_ALL(bufi, koff)                                               \
    {                                                                       \
        char* aL_ = (char*)&As[bufi][0];                                    \
        char* bL_ = (char*)&Bs[bufi][0];                                    \
        _Pragma("unroll")                                                   \
        for (int u = 0; u < 2; ++u)                                         \
            async_copy16(Ab + gaA[u] + (koff), aL_ + laA[u]);               \
        _Pragma("unroll")                                                   \
        for (int u = 0; u < 2; ++u)                                         \
            async_copy16(Bb + gaB[u] + (koff), bL_ + laB[u]);               \
    }

    // monolithic compute (tail only)
#define COMPUTE_MONO(bufi)                                                  \
    {                                                                       \
        const _Float16*      aP_ = &As[bufi][0];                            \
        const unsigned char* bP_ = &Bs[bufi][0];                            \
        f16x8 af[4][2], bf[4][2];                                           \
        _Pragma("unroll")                                                   \
        for (int i = 0; i < 4; ++i) {                                       \
            _Pragma("unroll")                                               \
            for (int h = 0; h < 2; ++h) {                                   \
                af[i][h] = *(const f16x8*)(aP_ + aOff[i][h]);               \
                bf[i][h] = bfrag(bP_ + bOff[i][h]);                         \
            }                                                               \
        }                                                                   \
        __builtin_amdgcn_s_setprio(1);                                      \
        _Pragma("unroll")                                                   \
        for (int h = 0; h < 2; ++h)                                         \
            _Pragma("unroll")                                               \
            for (int i = 0; i < 4; ++i)                                     \
                _Pragma("unroll")                                           \
                for (int j = 0; j < 4; ++j)                                 \
                    acc[i][j] = __builtin_amdgcn_mfma_f32_16x16x32_f16(     \
                        af[i][h], bf[j][h], acc[i][j], 0, 0, 0);            \
        __builtin_amdgcn_s_setprio(0);                                      \
    }

    // prologue: 2 K-tiles in flight; wait for buf0 only (8 -> 4 outstanding)
    STAGE_ALL(0, 0);
    STAGE_ALL(1, BK);
    asm volatile("s_waitcnt vmcnt(4)" ::: "memory");
    BAR;
    FENCE;

    // invariant at loop top: outstanding = 4 loads of K-tile t+1
    int cur = 0;
    for (int t = 0; t < NT - 2; ++t) {
        int b2 = cur + 2; if (b2 >= 3) b2 -= 3;
        const _Float16*      aP = &As[cur][0];
        const unsigned char* bP = &Bs[cur][0];
        char* aL = (char*)&As[b2][0];
        char* bL = (char*)&Bs[b2][0];
        const size_t ko2 = (size_t)(t + 2) * BK;

        f16x8 af0[4], af1[4];

        // ---- phase 0: A frags h=0, B cols 0-1 h=0; stage A ----
#pragma unroll
        for (int i = 0; i < 4; ++i) af0[i] = *(const f16x8*)(aP + aOff[i][0]);
        f16x8 b00 = bfrag(bP + bOff[0][0]);
        f16x8 b10 = bfrag(bP + bOff[1][0]);
#pragma unroll
        for (int u = 0; u < 2; ++u) async_copy16(Ab + gaA[u] + ko2, aL + laA[u]);
        FENCE; BAR;
        __builtin_amdgcn_s_setprio(1);
        MG(af0, b00, 0);
        MG(af0, b10, 1);
        __builtin_amdgcn_s_setprio(0);
        FENCE; BAR;

        // ---- phase 1: B cols 2-3 h=0; stage B ----
        f16x8 b20 = bfrag(bP + bOff[2][0]);
        f16x8 b30 = bfrag(bP + bOff[3][0]);
#pragma unroll
        for (int u = 0; u < 2; ++u) async_copy16(Bb + gaB[u] + ko2, bL + laB[u]);
        FENCE; BAR;
        __builtin_amdgcn_s_setprio(1);
        MG(af0, b20, 2);
        MG(af0, b30, 3);
        __builtin_amdgcn_s_setprio(0);
        FENCE; BAR;

        // ---- phase 2: A frags h=1, B cols 0-1 h=1 ----
#pragma unroll
        for (int i = 0; i < 4; ++i) af1[i] = *(const f16x8*)(aP + aOff[i][1]);
        f16x8 b01 = bfrag(bP + bOff[0][1]);
        f16x8 b11 = bfrag(bP + bOff[1][1]);
        FENCE; BAR;
        __builtin_amdgcn_s_setprio(1);
        MG(af1, b01, 0);
        MG(af1, b11, 1);
        __builtin_amdgcn_s_setprio(0);
        FENCE; BAR;

        // ---- phase 3: B cols 2-3 h=1; counted vmcnt (t+1 done, t+2 fly) ----
        f16x8 b21 = bfrag(bP + bOff[2][1]);
        f16x8 b31 = bfrag(bP + bOff[3][1]);
        asm volatile("s_waitcnt vmcnt(4)" ::: "memory");
        FENCE; BAR;
        __builtin_amdgcn_s_setprio(1);
        MG(af1, b21, 2);
        MG(af1, b31, 3);
        __builtin_amdgcn_s_setprio(0);
        FENCE; BAR;

        cur = cur + 1; if (cur >= 3) cur = 0;
    }

    // tail: t = NT-2 (data ready; 4 loads of NT-1 outstanding), then NT-1
    COMPUTE_MONO(cur);
    asm volatile("s_waitcnt vmcnt(0)" ::: "memory");
    BAR;
    FENCE;
    cur = cur + 1; if (cur >= 3) cur = 0;
    COMPUTE_MONO(cur);

#undef FENCE
#undef BAR
#undef MG
#undef STAGE_ALL
#undef COMPUTE_MONO

    // Epilogue: D[row=(lane>>4)*4+r][col=lane&15] per 16x16 tile, fp16-round
#pragma unroll
    for (int j = 0; j < 4; ++j) {
        int col = bn + wn + j * 16 + l16;
        float sb = scale_b[col];
#pragma unroll
        for (int i = 0; i < 4; ++i) {
#pragma unroll
            for (int r = 0; r < 4; ++r) {
                int row = bm + wm + i * 16 + quad * 4 + r;
                float v = acc[i][j][r] * sb;
                out[(size_t)row * H + col] = (float)(_Float16)v;
            }
        }
    }
}

extern "C" void kernel_launch(void* const* d_in, const int* in_sizes, int n_in,
                              void* d_out, int out_size, void* d_ws, size_t ws_size,
                              hipStream_t stream) {
    const float* input   = (const float*)d_in[0];   // [16384, 4096] fp32
    const float* weight  = (const float*)d_in[1];   // [4096, 4096] fp32
    const float* scale_b = (const float*)d_in[2];   // [1, 4096] fp32
    float* out = (float*)d_out;                     // [2048, 4096] (fp16 values)

    _Float16* aq = (_Float16*)d_ws;                               // 16 MB
    unsigned char* bt = (unsigned char*)d_ws + (size_t)MOUT * H * 2;  // 16 MB

    reduce_quant_a<<<(MOUT * H / 4) / 256, 256, 0, stream>>>(input, aq);
    quant_transpose_b<<<dim3(H / 64, H / 64), 256, 0, stream>>>(weight, bt);
    gemm_rs<<<dim3(H / BN, MOUT / BM), 512, 0, stream>>>(aq, bt, scale_b, out);
}